// Round 4
// baseline (350.501 us; speedup 1.0000x reference)
//
#include <hip/hip_runtime.h>

#define N_NODES 50000
#define N_EDGES 800000
#define M_IDX   25000
#define DMAX    64   // Poisson(16) degree; P(deg>=64) ~ 1e-19 -- safe pad

// ---------------------------------------------------------------------------
// Prep (once): scatter per-edge record {pos[t]-pos[s], src-bits} into the
// destination node's packed row pdata[t*DMAX+p]. Two independent edges per
// thread (2x memory-level parallelism; atomics issued before pos gathers).
// ---------------------------------------------------------------------------
__global__ __launch_bounds__(256) void prep_kernel(
    const int*   __restrict__ ei,     // [2,E]
    const float* __restrict__ pos,    // [N,3]
    int*         __restrict__ cnt,    // [N] (pre-zeroed)
    float4*      __restrict__ pdata,  // [N,DMAX] xyz = pseudo, w = src bits
    int E)
{
    const int e0 = blockIdx.x * 512 + threadIdx.x;
    const int e1 = e0 + 256;
    const bool v0 = e0 < E, v1 = e1 < E;
    int t0 = 0, s0 = 0, t1 = 0, s1 = 0;
    if (v0) { t0 = ei[E + e0]; s0 = ei[e0]; }
    if (v1) { t1 = ei[E + e1]; s1 = ei[e1]; }
    int p0 = 0, p1 = 0;
    if (v0) p0 = atomicAdd(&cnt[t0], 1);      // issue both atomics early;
    if (v1) p1 = atomicAdd(&cnt[t1], 1);      // pos gathers overlap their latency
    if (v0) {
        float4 pd;
        pd.x = pos[t0 * 3 + 0] - pos[s0 * 3 + 0];
        pd.y = pos[t0 * 3 + 1] - pos[s0 * 3 + 1];
        pd.z = pos[t0 * 3 + 2] - pos[s0 * 3 + 2];
        pd.w = __int_as_float(s0);
        if (p0 < DMAX) pdata[(size_t)t0 * DMAX + p0] = pd;
    }
    if (v1) {
        float4 pd;
        pd.x = pos[t1 * 3 + 0] - pos[s1 * 3 + 0];
        pd.y = pos[t1 * 3 + 1] - pos[s1 * 3 + 1];
        pd.z = pos[t1 * 3 + 2] - pos[s1 * 3 + 2];
        pd.w = __int_as_float(s1);
        if (p1 < DMAX) pdata[(size_t)t1 * DMAX + p1] = pd;
    }
}

// ---------------------------------------------------------------------------
// Fused layer, one WAVE per node. Lane = (edge-group eg = lane>>4) x
// (out-channel o = lane&15). Folded edge-MLP weights live in LDS (4 KB,
// folded cooperatively once per block -- kills the per-thread 64-float array
// the register allocator refused to keep resident in R1-R3). Each group
// walks edge slots eg, eg+4, ... two slots in flight; cross-group combine
// via shfl_xor(16/32); then mean + root GEMV + bias + ReLU.
// ---------------------------------------------------------------------------
template<int CI>
__global__ __launch_bounds__(256) void node_wave_kernel(
    const float4* __restrict__ pdata,  // [N,DMAX]
    const int*    __restrict__ cnt,    // [N]
    const float*  __restrict__ h_in,   // [N,CI]
    const float*  __restrict__ lin_w,  // [3, CI*16]
    const float*  __restrict__ lin_b,  // [CI*16]
    const float*  __restrict__ gamma,  // [CI*16]
    const float*  __restrict__ beta,   // [CI*16]
    const float*  __restrict__ root,   // [CI,16]
    const float*  __restrict__ bias,   // [16]
    float*        __restrict__ h_out,  // [N,16]
    int N)
{
    __shared__ float4 wlds[CI * 16];   // [i*16+o] = {W0,W1,W2,B}

    const int tid = threadIdx.x;
    if (tid < CI * 16) {               // cooperative fold: one (i,o) per thread
        const int j = tid;
        const float g = gamma[j];
        float4 w4;
        w4.x = lin_w[j] * g;
        w4.y = lin_w[CI * 16 + j] * g;
        w4.z = lin_w[2 * CI * 16 + j] * g;
        w4.w = fmaf(lin_b[j], g, beta[j]);
        wlds[j] = w4;
    }
    __syncthreads();

    const int lane = tid & 63;
    const int eg   = lane >> 4;        // edge group 0..3
    const int o    = lane & 15;        // out channel
    const int t    = blockIdx.x * 4 + (tid >> 6);   // N % 4 == 0: no guard

    const int deg = cnt[t];
    const int dl  = min(deg, DMAX);
    const float4* __restrict__ row = pdata + (size_t)t * DMAX;

    float acc = 0.f;
    for (int p = eg; p < dl; p += 8) {     // 2 slots (p, p+4) in flight
        const int  p1 = p + 4;
        const bool v1 = p1 < dl;
        float4 pdA = row[p];
        float4 pdB = v1 ? row[p1] : pdA;
        const float4* xa = (const float4*)(h_in + (size_t)__float_as_int(pdA.w) * CI);
        const float4* xb = (const float4*)(h_in + (size_t)__float_as_int(pdB.w) * CI);
        float xA[CI], xB[CI];
#pragma unroll
        for (int q = 0; q < CI / 4; ++q) {
            float4 a = xa[q];
            xA[4 * q + 0] = a.x; xA[4 * q + 1] = a.y;
            xA[4 * q + 2] = a.z; xA[4 * q + 3] = a.w;
            float4 b = xb[q];
            xB[4 * q + 0] = b.x; xB[4 * q + 1] = b.y;
            xB[4 * q + 2] = b.z; xB[4 * q + 3] = b.w;
        }
        float eA = 0.f, eB = 0.f;
#pragma unroll
        for (int i = 0; i < CI; ++i) {
            float4 w4 = wlds[i * 16 + o];
            float wA = fmaf(pdA.z, w4.z, fmaf(pdA.y, w4.y, fmaf(pdA.x, w4.x, w4.w)));
            eA = fmaf(xA[i], fmaxf(wA, 0.f), eA);
            float wB = fmaf(pdB.z, w4.z, fmaf(pdB.y, w4.y, fmaf(pdB.x, w4.x, w4.w)));
            eB = fmaf(xB[i], fmaxf(wB, 0.f), eB);
        }
        acc += eA + (v1 ? eB : 0.f);
    }
    // combine the 4 edge groups (all lanes end with the full sum for their o)
    acc += __shfl_xor(acc, 16);
    acc += __shfl_xor(acc, 32);

    // mean + root GEMV + bias + ReLU (group 0 stores)
    float r = fmaf(acc, 1.0f / fmaxf((float)deg, 1.0f), bias[o]);
    const float4* hp = (const float4*)(h_in + (size_t)t * CI);
#pragma unroll
    for (int q = 0; q < CI / 4; ++q) {
        float4 v = hp[q];
        r = fmaf(v.x, root[(4 * q + 0) * 16 + o], r);
        r = fmaf(v.y, root[(4 * q + 1) * 16 + o], r);
        r = fmaf(v.z, root[(4 * q + 2) * 16 + o], r);
        r = fmaf(v.w, root[(4 * q + 3) * 16 + o], r);
    }
    if (eg == 0) h_out[t * 16 + o] = fmaxf(r, 0.f);
}

// ---------------------------------------------------------------------------
// Output gather: out = [h[idx] (M*16) | pos[idx] (M*3) | batch[idx] (M)]
// ---------------------------------------------------------------------------
__global__ __launch_bounds__(256) void gather_kernel(
    const float* __restrict__ h,
    const float* __restrict__ pos,
    const int*   __restrict__ batch,
    const int*   __restrict__ idx,
    float*       __restrict__ out,
    int M)
{
    int j = blockIdx.x * blockDim.x + threadIdx.x;
    if (j >= M) return;
    int n = idx[j];
    float4*       o4 = (float4*)out + (size_t)j * 4;
    const float4* h4 = (const float4*)(h + (size_t)n * 16);
    o4[0] = h4[0]; o4[1] = h4[1]; o4[2] = h4[2]; o4[3] = h4[3];
    float* po = out + (size_t)M * 16 + (size_t)j * 3;
    po[0] = pos[n * 3 + 0];
    po[1] = pos[n * 3 + 1];
    po[2] = pos[n * 3 + 2];
    ((int*)out)[(size_t)M * 19 + j] = batch[n];
}

extern "C" void kernel_launch(void* const* d_in, const int* in_sizes, int n_in,
                              void* d_out, int out_size, void* d_ws, size_t ws_size,
                              hipStream_t stream) {
    const float* x      = (const float*)d_in[0];
    const float* pos    = (const float*)d_in[1];
    const float* lin_w0 = (const float*)d_in[2];
    const float* lin_b0 = (const float*)d_in[3];
    const float* gamma0 = (const float*)d_in[4];
    const float* beta0  = (const float*)d_in[5];
    const float* root0  = (const float*)d_in[6];
    const float* bias0  = (const float*)d_in[7];
    const float* lin_w1 = (const float*)d_in[8];
    const float* lin_b1 = (const float*)d_in[9];
    const float* gamma1 = (const float*)d_in[10];
    const float* beta1  = (const float*)d_in[11];
    const float* root1  = (const float*)d_in[12];
    const float* bias1  = (const float*)d_in[13];
    const float* lin_w2 = (const float*)d_in[14];
    const float* lin_b2 = (const float*)d_in[15];
    const float* gamma2 = (const float*)d_in[16];
    const float* beta2  = (const float*)d_in[17];
    const float* root2  = (const float*)d_in[18];
    const float* bias2  = (const float*)d_in[19];
    const int*   batch  = (const int*)d_in[20];
    const int*   idx    = (const int*)d_in[21];
    const int*   ei     = (const int*)d_in[22];
    float*       out    = (float*)d_out;

    // workspace layout (all 16B aligned)
    float4* pdata = (float4*)d_ws;                                // N*DMAX float4 (51.2 MB)
    float*  hA    = (float*)(pdata + (size_t)N_NODES * DMAX);     // N*16 floats
    float*  hB    = hA + (size_t)N_NODES * 16;                    // N*16 floats
    int*    cnt   = (int*)(hB + (size_t)N_NODES * 16);            // N ints

    hipMemsetAsync(cnt, 0, N_NODES * sizeof(int), stream);
    prep_kernel<<<(N_EDGES + 511) / 512, 256, 0, stream>>>(ei, pos, cnt, pdata, N_EDGES);

    const int NB = N_NODES / 4;   // one wave per node, 4 nodes per block

    node_wave_kernel<8><<<NB, 256, 0, stream>>>(pdata, cnt, x,
        lin_w0, lin_b0, gamma0, beta0, root0, bias0, hA, N_NODES);
    node_wave_kernel<16><<<NB, 256, 0, stream>>>(pdata, cnt, hA,
        lin_w1, lin_b1, gamma1, beta1, root1, bias1, hB, N_NODES);
    node_wave_kernel<16><<<NB, 256, 0, stream>>>(pdata, cnt, hB,
        lin_w2, lin_b2, gamma2, beta2, root2, bias2, hA, N_NODES);

    gather_kernel<<<(M_IDX + 255) / 256, 256, 0, stream>>>(hA, pos, batch, idx, out, M_IDX);
}

// Round 5
// 337.102 us; speedup vs baseline: 1.0397x; 1.0397x over previous
//
#include <hip/hip_runtime.h>

#define N_NODES 50000
#define N_EDGES 800000
#define M_IDX   25000
#define DMAX    64   // Poisson(16) degree; P(deg>=64) ~ 1e-19 -- safe pad

// ---------------------------------------------------------------------------
// Prep (once): scatter per-edge record {pos[t]-pos[s], src-bits} into the
// destination node's packed row pdata[t*DMAX+p]. Two independent edges per
// thread (atomics issued before pos gathers).
// ---------------------------------------------------------------------------
__global__ __launch_bounds__(256) void prep_kernel(
    const int*   __restrict__ ei,     // [2,E]
    const float* __restrict__ pos,    // [N,3]
    int*         __restrict__ cnt,    // [N] (pre-zeroed)
    float4*      __restrict__ pdata,  // [N,DMAX] xyz = pseudo, w = src bits
    int E)
{
    const int e0 = blockIdx.x * 512 + threadIdx.x;
    const int e1 = e0 + 256;
    const bool v0 = e0 < E, v1 = e1 < E;
    int t0 = 0, s0 = 0, t1 = 0, s1 = 0;
    if (v0) { t0 = ei[E + e0]; s0 = ei[e0]; }
    if (v1) { t1 = ei[E + e1]; s1 = ei[e1]; }
    int p0 = 0, p1 = 0;
    if (v0) p0 = atomicAdd(&cnt[t0], 1);
    if (v1) p1 = atomicAdd(&cnt[t1], 1);
    if (v0) {
        float4 pd;
        pd.x = pos[t0 * 3 + 0] - pos[s0 * 3 + 0];
        pd.y = pos[t0 * 3 + 1] - pos[s0 * 3 + 1];
        pd.z = pos[t0 * 3 + 2] - pos[s0 * 3 + 2];
        pd.w = __int_as_float(s0);
        if (p0 < DMAX) pdata[(size_t)t0 * DMAX + p0] = pd;
    }
    if (v1) {
        float4 pd;
        pd.x = pos[t1 * 3 + 0] - pos[s1 * 3 + 0];
        pd.y = pos[t1 * 3 + 1] - pos[s1 * 3 + 1];
        pd.z = pos[t1 * 3 + 2] - pos[s1 * 3 + 2];
        pd.w = __int_as_float(s1);
        if (p1 < DMAX) pdata[(size_t)t1 * DMAX + p1] = pd;
    }
}

// load IQ contiguous floats (IQ = 4 or 2), aligned
template<int IQ>
__device__ __forceinline__ void load_q(float* dst, const float* src) {
    if constexpr (IQ == 4) {
        float4 v = *(const float4*)src;
        dst[0] = v.x; dst[1] = v.y; dst[2] = v.z; dst[3] = v.w;
    } else {
        float2 v = *(const float2*)src;
        dst[0] = v.x; dst[1] = v.y;
    }
}

// ---------------------------------------------------------------------------
// Fused layer, one WAVE per node; lane = (i-quarter eg = lane>>4) x
// (out-channel o = lane&15). Lane (eg,o) covers input channels
// i in [eg*CI/4, (eg+1)*CI/4): only CI folded weights per lane (registers,
// no spill/remat -- the R1-R4 failure mode), and ONE float4 of x[src] per
// edge (4 groups read the 64B row exactly once; was 16x redundant).
// All lanes walk all dl edges: VALU is perfectly partitioned (64 lanes x
// CI/4 pairs = CI*16, zero duplication). Finish: contrib = acc/deg +
// root_partial, shfl_xor(16/32), +bias, ReLU, eg==0 stores.
// ---------------------------------------------------------------------------
template<int CI>
__global__ __launch_bounds__(256) void node_wave_kernel(
    const float4* __restrict__ pdata,  // [N,DMAX]
    const int*    __restrict__ cnt,    // [N]
    const float*  __restrict__ h_in,   // [N,CI]
    const float*  __restrict__ lin_w,  // [3, CI*16]
    const float*  __restrict__ lin_b,  // [CI*16]
    const float*  __restrict__ gamma,  // [CI*16]
    const float*  __restrict__ beta,   // [CI*16]
    const float*  __restrict__ root,   // [CI,16]
    const float*  __restrict__ bias,   // [16]
    float*        __restrict__ h_out,  // [N,16]
    int N)
{
    constexpr int IQ = CI / 4;         // input channels per lane
    const int tid  = threadIdx.x;
    const int lane = tid & 63;
    const int eg   = lane >> 4;        // i-quarter 0..3
    const int o    = lane & 15;        // out channel
    const int t    = blockIdx.x * 4 + (tid >> 6);   // N % 4 == 0

    // fold Linear + eval-mode BN affine for this lane's (i-quarter, o)
    float W0[IQ], W1[IQ], W2[IQ], B[IQ];
#pragma unroll
    for (int z = 0; z < IQ; ++z) {
        const int j = (eg * IQ + z) * 16 + o;
        const float g = gamma[j];
        W0[z] = lin_w[j] * g;
        W1[z] = lin_w[CI * 16 + j] * g;
        W2[z] = lin_w[2 * CI * 16 + j] * g;
        B[z]  = fmaf(lin_b[j], g, beta[j]);
    }

    const int deg = cnt[t];
    const int dl  = min(deg, DMAX);
    const float4* __restrict__ row = pdata + (size_t)t * DMAX;
    const float*  __restrict__ xq_base = h_in + eg * IQ;

    float acc = 0.f;
    int p = 0;
    for (; p + 2 <= dl; p += 2) {      // 2 edges in flight
        float4 pdA = row[p];
        float4 pdB = row[p + 1];
        const int sA = __float_as_int(pdA.w);
        const int sB = __float_as_int(pdB.w);
        float xA[IQ], xB[IQ];
        load_q<IQ>(xA, xq_base + (size_t)sA * CI);
        load_q<IQ>(xB, xq_base + (size_t)sB * CI);
        float eA = 0.f, eB = 0.f;
#pragma unroll
        for (int z = 0; z < IQ; ++z) {
            float wA = fmaf(pdA.z, W2[z], fmaf(pdA.y, W1[z], fmaf(pdA.x, W0[z], B[z])));
            eA = fmaf(xA[z], fmaxf(wA, 0.f), eA);
            float wB = fmaf(pdB.z, W2[z], fmaf(pdB.y, W1[z], fmaf(pdB.x, W0[z], B[z])));
            eB = fmaf(xB[z], fmaxf(wB, 0.f), eB);
        }
        acc += eA + eB;
    }
    if (p < dl) {                      // tail edge
        float4 pdA = row[p];
        const int sA = __float_as_int(pdA.w);
        float xA[IQ];
        load_q<IQ>(xA, xq_base + (size_t)sA * CI);
#pragma unroll
        for (int z = 0; z < IQ; ++z) {
            float wA = fmaf(pdA.z, W2[z], fmaf(pdA.y, W1[z], fmaf(pdA.x, W0[z], B[z])));
            acc = fmaf(xA[z], fmaxf(wA, 0.f), acc);
        }
    }

    // root partial for this lane's i-quarter
    float xT[IQ];
    load_q<IQ>(xT, xq_base + (size_t)t * CI);
    float rp = 0.f;
#pragma unroll
    for (int z = 0; z < IQ; ++z)
        rp = fmaf(xT[z], root[(eg * IQ + z) * 16 + o], rp);

    // mean is linear: sum (acc/deg + rp) over the 4 i-quarter groups
    float contrib = fmaf(acc, 1.0f / fmaxf((float)deg, 1.0f), rp);
    contrib += __shfl_xor(contrib, 16);
    contrib += __shfl_xor(contrib, 32);

    if (eg == 0) h_out[t * 16 + o] = fmaxf(contrib + bias[o], 0.f);
}

// ---------------------------------------------------------------------------
// Output gather: out = [h[idx] (M*16) | pos[idx] (M*3) | batch[idx] (M)]
// ---------------------------------------------------------------------------
__global__ __launch_bounds__(256) void gather_kernel(
    const float* __restrict__ h,
    const float* __restrict__ pos,
    const int*   __restrict__ batch,
    const int*   __restrict__ idx,
    float*       __restrict__ out,
    int M)
{
    int j = blockIdx.x * blockDim.x + threadIdx.x;
    if (j >= M) return;
    int n = idx[j];
    float4*       o4 = (float4*)out + (size_t)j * 4;
    const float4* h4 = (const float4*)(h + (size_t)n * 16);
    o4[0] = h4[0]; o4[1] = h4[1]; o4[2] = h4[2]; o4[3] = h4[3];
    float* po = out + (size_t)M * 16 + (size_t)j * 3;
    po[0] = pos[n * 3 + 0];
    po[1] = pos[n * 3 + 1];
    po[2] = pos[n * 3 + 2];
    ((int*)out)[(size_t)M * 19 + j] = batch[n];
}

extern "C" void kernel_launch(void* const* d_in, const int* in_sizes, int n_in,
                              void* d_out, int out_size, void* d_ws, size_t ws_size,
                              hipStream_t stream) {
    const float* x      = (const float*)d_in[0];
    const float* pos    = (const float*)d_in[1];
    const float* lin_w0 = (const float*)d_in[2];
    const float* lin_b0 = (const float*)d_in[3];
    const float* gamma0 = (const float*)d_in[4];
    const float* beta0  = (const float*)d_in[5];
    const float* root0  = (const float*)d_in[6];
    const float* bias0  = (const float*)d_in[7];
    const float* lin_w1 = (const float*)d_in[8];
    const float* lin_b1 = (const float*)d_in[9];
    const float* gamma1 = (const float*)d_in[10];
    const float* beta1  = (const float*)d_in[11];
    const float* root1  = (const float*)d_in[12];
    const float* bias1  = (const float*)d_in[13];
    const float* lin_w2 = (const float*)d_in[14];
    const float* lin_b2 = (const float*)d_in[15];
    const float* gamma2 = (const float*)d_in[16];
    const float* beta2  = (const float*)d_in[17];
    const float* root2  = (const float*)d_in[18];
    const float* bias2  = (const float*)d_in[19];
    const int*   batch  = (const int*)d_in[20];
    const int*   idx    = (const int*)d_in[21];
    const int*   ei     = (const int*)d_in[22];
    float*       out    = (float*)d_out;

    // workspace layout (all 16B aligned)
    float4* pdata = (float4*)d_ws;                                // N*DMAX float4 (51.2 MB)
    float*  hA    = (float*)(pdata + (size_t)N_NODES * DMAX);     // N*16 floats
    float*  hB    = hA + (size_t)N_NODES * 16;                    // N*16 floats
    int*    cnt   = (int*)(hB + (size_t)N_NODES * 16);            // N ints

    hipMemsetAsync(cnt, 0, N_NODES * sizeof(int), stream);
    prep_kernel<<<(N_EDGES + 511) / 512, 256, 0, stream>>>(ei, pos, cnt, pdata, N_EDGES);

    const int NB = N_NODES / 4;   // one wave per node, 4 waves per block

    node_wave_kernel<8><<<NB, 256, 0, stream>>>(pdata, cnt, x,
        lin_w0, lin_b0, gamma0, beta0, root0, bias0, hA, N_NODES);
    node_wave_kernel<16><<<NB, 256, 0, stream>>>(pdata, cnt, hA,
        lin_w1, lin_b1, gamma1, beta1, root1, bias1, hB, N_NODES);
    node_wave_kernel<16><<<NB, 256, 0, stream>>>(pdata, cnt, hB,
        lin_w2, lin_b2, gamma2, beta2, root2, bias2, hA, N_NODES);

    gather_kernel<<<(M_IDX + 255) / 256, 256, 0, stream>>>(hA, pos, batch, idx, out, M_IDX);
}

// Round 6
// 329.798 us; speedup vs baseline: 1.0628x; 1.0221x over previous
//
#include <hip/hip_runtime.h>

#define N_NODES 50000
#define N_EDGES 800000
#define M_IDX   25000
#define DMAX    64   // Poisson(16) degree; P(deg>=64) ~ 1e-19 -- safe pad

// ---------------------------------------------------------------------------
// Fold Linear + eval-mode BN affine into a global table, once.
// wtab[l*256 + i*16+o] = {W0,W1,W2,B} for layer l. 12 KB total, L1-resident.
// This removes the in-loop weight fold the compiler insisted on
// rematerializing in R1-R5 (VGPR_Count 28-60 across all attempts).
// ---------------------------------------------------------------------------
__global__ __launch_bounds__(256) void fold_kernel(
    const float* __restrict__ lw0, const float* __restrict__ lb0,
    const float* __restrict__ g0,  const float* __restrict__ b0,
    const float* __restrict__ lw1, const float* __restrict__ lb1,
    const float* __restrict__ g1,  const float* __restrict__ b1,
    const float* __restrict__ lw2, const float* __restrict__ lb2,
    const float* __restrict__ g2,  const float* __restrict__ b2,
    float4* __restrict__ wtab)
{
    const int l = blockIdx.x, j = threadIdx.x;
    const float *lw, *lb, *gm, *bt; int d;
    if (l == 0)      { lw = lw0; lb = lb0; gm = g0; bt = b0; d = 128; }
    else if (l == 1) { lw = lw1; lb = lb1; gm = g1; bt = b1; d = 256; }
    else             { lw = lw2; lb = lb2; gm = g2; bt = b2; d = 256; }
    if (j < d) {
        const float g = gm[j];
        float4 w4;
        w4.x = lw[j] * g;
        w4.y = lw[d + j] * g;
        w4.z = lw[2 * d + j] * g;
        w4.w = fmaf(lb[j], g, bt[j]);
        wtab[l * 256 + j] = w4;
    }
}

// ---------------------------------------------------------------------------
// Prep (once): scatter per-edge record {pos[t]-pos[s], src-bits} into the
// destination node's packed row pdata[t*DMAX+p]. Two independent edges per
// thread (atomics issued before pos gathers).
// ---------------------------------------------------------------------------
__global__ __launch_bounds__(256) void prep_kernel(
    const int*   __restrict__ ei,     // [2,E]
    const float* __restrict__ pos,    // [N,3]
    int*         __restrict__ cnt,    // [N] (pre-zeroed)
    float4*      __restrict__ pdata,  // [N,DMAX] xyz = pseudo, w = src bits
    int E)
{
    const int e0 = blockIdx.x * 512 + threadIdx.x;
    const int e1 = e0 + 256;
    const bool v0 = e0 < E, v1 = e1 < E;
    int t0 = 0, s0 = 0, t1 = 0, s1 = 0;
    if (v0) { t0 = ei[E + e0]; s0 = ei[e0]; }
    if (v1) { t1 = ei[E + e1]; s1 = ei[e1]; }
    int p0 = 0, p1 = 0;
    if (v0) p0 = atomicAdd(&cnt[t0], 1);
    if (v1) p1 = atomicAdd(&cnt[t1], 1);
    if (v0) {
        float4 pd;
        pd.x = pos[t0 * 3 + 0] - pos[s0 * 3 + 0];
        pd.y = pos[t0 * 3 + 1] - pos[s0 * 3 + 1];
        pd.z = pos[t0 * 3 + 2] - pos[s0 * 3 + 2];
        pd.w = __int_as_float(s0);
        if (p0 < DMAX) pdata[(size_t)t0 * DMAX + p0] = pd;
    }
    if (v1) {
        float4 pd;
        pd.x = pos[t1 * 3 + 0] - pos[s1 * 3 + 0];
        pd.y = pos[t1 * 3 + 1] - pos[s1 * 3 + 1];
        pd.z = pos[t1 * 3 + 2] - pos[s1 * 3 + 2];
        pd.w = __int_as_float(s1);
        if (p1 < DMAX) pdata[(size_t)t1 * DMAX + p1] = pd;
    }
}

// load IQ contiguous floats (IQ = 4 or 2), aligned
template<int IQ>
__device__ __forceinline__ void load_q(float* dst, const float* src) {
    if constexpr (IQ == 4) {
        float4 v = *(const float4*)src;
        dst[0] = v.x; dst[1] = v.y; dst[2] = v.z; dst[3] = v.w;
    } else {
        float2 v = *(const float2*)src;
        dst[0] = v.x; dst[1] = v.y;
    }
}

// ---------------------------------------------------------------------------
// Fused layer, one WAVE per node; lane = (i-quarter eg = lane>>4) x
// (out-channel o = lane&15). Lane (eg,o) covers input channels
// i in [eg*IQ, (eg+1)*IQ) and reads its IQ prefolded float4 weights from
// wtab (L1-hit broadcasts; nothing left for the compiler to rematerialize).
// One float4 of x[src] per edge per group (row read exactly once per wave).
// Finish: contrib = acc/deg + root_partial, shfl_xor(16/32), +bias, ReLU.
// ---------------------------------------------------------------------------
template<int CI>
__global__ __launch_bounds__(256) void node_wave_kernel(
    const float4* __restrict__ pdata,  // [N,DMAX]
    const int*    __restrict__ cnt,    // [N]
    const float*  __restrict__ h_in,   // [N,CI]
    const float4* __restrict__ wt_l,   // [CI*16] prefolded {W0,W1,W2,B}
    const float*  __restrict__ root,   // [CI,16]
    const float*  __restrict__ bias,   // [16]
    float*        __restrict__ h_out,  // [N,16]
    int N)
{
    constexpr int IQ = CI / 4;         // input channels per lane
    const int tid  = threadIdx.x;
    const int lane = tid & 63;
    const int eg   = lane >> 4;        // i-quarter 0..3
    const int o    = lane & 15;        // out channel
    const int t    = blockIdx.x * 4 + (tid >> 6);   // N % 4 == 0

    // this lane's prefolded weights: wt[z*16], z = 0..IQ-1
    const float4* __restrict__ wt = wt_l + (eg * IQ) * 16 + o;
    float4 w4[IQ];
#pragma unroll
    for (int z = 0; z < IQ; ++z) w4[z] = wt[z * 16];

    const int deg = cnt[t];
    const int dl  = min(deg, DMAX);
    const float4* __restrict__ row = pdata + (size_t)t * DMAX;
    const float*  __restrict__ xq_base = h_in + eg * IQ;

    float acc = 0.f;
    int p = 0;
    for (; p + 2 <= dl; p += 2) {      // 2 edges in flight
        float4 pdA = row[p];
        float4 pdB = row[p + 1];
        const int sA = __float_as_int(pdA.w);
        const int sB = __float_as_int(pdB.w);
        float xA[IQ], xB[IQ];
        load_q<IQ>(xA, xq_base + (size_t)sA * CI);
        load_q<IQ>(xB, xq_base + (size_t)sB * CI);
        float eA = 0.f, eB = 0.f;
#pragma unroll
        for (int z = 0; z < IQ; ++z) {
            float wA = fmaf(pdA.z, w4[z].z, fmaf(pdA.y, w4[z].y, fmaf(pdA.x, w4[z].x, w4[z].w)));
            eA = fmaf(xA[z], fmaxf(wA, 0.f), eA);
            float wB = fmaf(pdB.z, w4[z].z, fmaf(pdB.y, w4[z].y, fmaf(pdB.x, w4[z].x, w4[z].w)));
            eB = fmaf(xB[z], fmaxf(wB, 0.f), eB);
        }
        acc += eA + eB;
    }
    if (p < dl) {                      // tail edge
        float4 pdA = row[p];
        const int sA = __float_as_int(pdA.w);
        float xA[IQ];
        load_q<IQ>(xA, xq_base + (size_t)sA * CI);
#pragma unroll
        for (int z = 0; z < IQ; ++z) {
            float wA = fmaf(pdA.z, w4[z].z, fmaf(pdA.y, w4[z].y, fmaf(pdA.x, w4[z].x, w4[z].w)));
            acc = fmaf(xA[z], fmaxf(wA, 0.f), acc);
        }
    }

    // root partial for this lane's i-quarter
    float xT[IQ];
    load_q<IQ>(xT, xq_base + (size_t)t * CI);
    float rp = 0.f;
#pragma unroll
    for (int z = 0; z < IQ; ++z)
        rp = fmaf(xT[z], root[(eg * IQ + z) * 16 + o], rp);

    // mean is linear: sum (acc/deg + rp) over the 4 i-quarter groups
    float contrib = fmaf(acc, 1.0f / fmaxf((float)deg, 1.0f), rp);
    contrib += __shfl_xor(contrib, 16);
    contrib += __shfl_xor(contrib, 32);

    if (eg == 0) h_out[t * 16 + o] = fmaxf(contrib + bias[o], 0.f);
}

// ---------------------------------------------------------------------------
// Output gather: out = [h[idx] (M*16) | pos[idx] (M*3) | batch[idx] (M)]
// ---------------------------------------------------------------------------
__global__ __launch_bounds__(256) void gather_kernel(
    const float* __restrict__ h,
    const float* __restrict__ pos,
    const int*   __restrict__ batch,
    const int*   __restrict__ idx,
    float*       __restrict__ out,
    int M)
{
    int j = blockIdx.x * blockDim.x + threadIdx.x;
    if (j >= M) return;
    int n = idx[j];
    float4*       o4 = (float4*)out + (size_t)j * 4;
    const float4* h4 = (const float4*)(h + (size_t)n * 16);
    o4[0] = h4[0]; o4[1] = h4[1]; o4[2] = h4[2]; o4[3] = h4[3];
    float* po = out + (size_t)M * 16 + (size_t)j * 3;
    po[0] = pos[n * 3 + 0];
    po[1] = pos[n * 3 + 1];
    po[2] = pos[n * 3 + 2];
    ((int*)out)[(size_t)M * 19 + j] = batch[n];
}

extern "C" void kernel_launch(void* const* d_in, const int* in_sizes, int n_in,
                              void* d_out, int out_size, void* d_ws, size_t ws_size,
                              hipStream_t stream) {
    const float* x      = (const float*)d_in[0];
    const float* pos    = (const float*)d_in[1];
    const float* lin_w0 = (const float*)d_in[2];
    const float* lin_b0 = (const float*)d_in[3];
    const float* gamma0 = (const float*)d_in[4];
    const float* beta0  = (const float*)d_in[5];
    const float* root0  = (const float*)d_in[6];
    const float* bias0  = (const float*)d_in[7];
    const float* lin_w1 = (const float*)d_in[8];
    const float* lin_b1 = (const float*)d_in[9];
    const float* gamma1 = (const float*)d_in[10];
    const float* beta1  = (const float*)d_in[11];
    const float* root1  = (const float*)d_in[12];
    const float* bias1  = (const float*)d_in[13];
    const float* lin_w2 = (const float*)d_in[14];
    const float* lin_b2 = (const float*)d_in[15];
    const float* gamma2 = (const float*)d_in[16];
    const float* beta2  = (const float*)d_in[17];
    const float* root2  = (const float*)d_in[18];
    const float* bias2  = (const float*)d_in[19];
    const int*   batch  = (const int*)d_in[20];
    const int*   idx    = (const int*)d_in[21];
    const int*   ei     = (const int*)d_in[22];
    float*       out    = (float*)d_out;

    // workspace layout (all 16B aligned)
    float4* pdata = (float4*)d_ws;                                // N*DMAX float4 (51.2 MB)
    float*  hA    = (float*)(pdata + (size_t)N_NODES * DMAX);     // N*16 floats
    float*  hB    = hA + (size_t)N_NODES * 16;                    // N*16 floats
    int*    cnt   = (int*)(hB + (size_t)N_NODES * 16);            // N ints
    float4* wtab  = (float4*)(cnt + N_NODES);                     // 3*256 float4 (12 KB)

    hipMemsetAsync(cnt, 0, N_NODES * sizeof(int), stream);
    fold_kernel<<<3, 256, 0, stream>>>(lin_w0, lin_b0, gamma0, beta0,
                                       lin_w1, lin_b1, gamma1, beta1,
                                       lin_w2, lin_b2, gamma2, beta2, wtab);
    prep_kernel<<<(N_EDGES + 511) / 512, 256, 0, stream>>>(ei, pos, cnt, pdata, N_EDGES);

    const int NB = N_NODES / 4;   // one wave per node, 4 waves per block

    node_wave_kernel<8><<<NB, 256, 0, stream>>>(pdata, cnt, x,
        wtab, root0, bias0, hA, N_NODES);
    node_wave_kernel<16><<<NB, 256, 0, stream>>>(pdata, cnt, hA,
        wtab + 256, root1, bias1, hB, N_NODES);
    node_wave_kernel<16><<<NB, 256, 0, stream>>>(pdata, cnt, hB,
        wtab + 512, root2, bias2, hA, N_NODES);

    gather_kernel<<<(M_IDX + 255) / 256, 256, 0, stream>>>(hA, pos, batch, idx, out, M_IDX);
}

// Round 7
// 324.256 us; speedup vs baseline: 1.0809x; 1.0171x over previous
//
#include <hip/hip_runtime.h>

#define N_NODES 50000
#define N_EDGES 800000
#define M_IDX   25000
#define DMAX    64   // Poisson(16) degree; P(deg>=64) ~ 1e-19 -- safe pad

typedef float v2f __attribute__((ext_vector_type(2)));

// ---------------------------------------------------------------------------
// Prep (once): scatter per-edge record {pos[t]-pos[s], src-bits} into the
// destination node's packed row pdata[t*DMAX+p]. Two independent edges per
// thread. Blocks 0-2 additionally fold Linear+BN into wtab (fused fold
// dispatch): wtab[l*256 + i*16+o] = {W0,W1,W2,B}.
// ---------------------------------------------------------------------------
__global__ __launch_bounds__(256) void prep_kernel(
    const int*   __restrict__ ei,     // [2,E]
    const float* __restrict__ pos,    // [N,3]
    int*         __restrict__ cnt,    // [N] (pre-zeroed)
    float4*      __restrict__ pdata,  // [N,DMAX] xyz = pseudo, w = src bits
    const float* __restrict__ lw0, const float* __restrict__ lb0,
    const float* __restrict__ g0,  const float* __restrict__ b0,
    const float* __restrict__ lw1, const float* __restrict__ lb1,
    const float* __restrict__ g1,  const float* __restrict__ b1,
    const float* __restrict__ lw2, const float* __restrict__ lb2,
    const float* __restrict__ g2,  const float* __restrict__ b2,
    float4*      __restrict__ wtab,   // [3*256]
    int E)
{
    // fused fold: first 3 blocks also write the folded weight table
    if (blockIdx.x < 3) {
        const int l = blockIdx.x, j = threadIdx.x;
        const float *lw, *lb, *gm, *bt; int d;
        if (l == 0)      { lw = lw0; lb = lb0; gm = g0; bt = b0; d = 128; }
        else if (l == 1) { lw = lw1; lb = lb1; gm = g1; bt = b1; d = 256; }
        else             { lw = lw2; lb = lb2; gm = g2; bt = b2; d = 256; }
        if (j < d) {
            const float g = gm[j];
            float4 w4;
            w4.x = lw[j] * g;
            w4.y = lw[d + j] * g;
            w4.z = lw[2 * d + j] * g;
            w4.w = fmaf(lb[j], g, bt[j]);
            wtab[l * 256 + j] = w4;
        }
    }

    const int e0 = blockIdx.x * 512 + threadIdx.x;
    const int e1 = e0 + 256;
    const bool v0 = e0 < E, v1 = e1 < E;
    int t0 = 0, s0 = 0, t1 = 0, s1 = 0;
    if (v0) { t0 = ei[E + e0]; s0 = ei[e0]; }
    if (v1) { t1 = ei[E + e1]; s1 = ei[e1]; }
    int p0 = 0, p1 = 0;
    if (v0) p0 = atomicAdd(&cnt[t0], 1);
    if (v1) p1 = atomicAdd(&cnt[t1], 1);
    if (v0) {
        float4 pd;
        pd.x = pos[t0 * 3 + 0] - pos[s0 * 3 + 0];
        pd.y = pos[t0 * 3 + 1] - pos[s0 * 3 + 1];
        pd.z = pos[t0 * 3 + 2] - pos[s0 * 3 + 2];
        pd.w = __int_as_float(s0);
        if (p0 < DMAX) pdata[(size_t)t0 * DMAX + p0] = pd;
    }
    if (v1) {
        float4 pd;
        pd.x = pos[t1 * 3 + 0] - pos[s1 * 3 + 0];
        pd.y = pos[t1 * 3 + 1] - pos[s1 * 3 + 1];
        pd.z = pos[t1 * 3 + 2] - pos[s1 * 3 + 2];
        pd.w = __int_as_float(s1);
        if (p1 < DMAX) pdata[(size_t)t1 * DMAX + p1] = pd;
    }
}

// load this lane's i-quarter of row s as v2f pairs (row = 4*IQ floats)
template<int IQ>
__device__ __forceinline__ void load_x(const float* __restrict__ h, int s, int eg, v2f* xv) {
    if constexpr (IQ == 4) {
        float4 v = ((const float4*)h)[s * 4 + eg];
        xv[0] = (v2f){v.x, v.y};
        xv[1] = (v2f){v.z, v.w};
    } else {
        float2 v = ((const float2*)h)[s * 4 + eg];
        xv[0] = (v2f){v.x, v.y};
    }
}

// ---------------------------------------------------------------------------
// Fused layer, PERSISTENT waves: 8192 waves (8/SIMD exactly), each wave
// grid-strides over ~6 nodes. Lane = (i-quarter eg, out-channel o).
// Folded weights / root / bias are node-loop-invariant -> loaded once per
// wave (amortized over ~100 edges even if the compiler sinks them).
// Inner loop: packed f32 math (v_pk_fma_f32), register-rotated pdata
// prefetch, masked odd-degree tail. Finish per node: contrib = acc/deg +
// root_partial, shfl_xor(16/32), +bias, ReLU, eg==0 stores.
// ---------------------------------------------------------------------------
template<int CI>
__global__ __launch_bounds__(256) void node_wave_kernel(
    const float4* __restrict__ pdata,  // [N,DMAX]
    const int*    __restrict__ cnt,    // [N]
    const float*  __restrict__ h_in,   // [N,CI]
    const float4* __restrict__ wt_l,   // [CI*16] prefolded {W0,W1,W2,B}
    const float*  __restrict__ root,   // [CI,16]
    const float*  __restrict__ bias,   // [16]
    float*        __restrict__ h_out,  // [N,16]
    int N)
{
    constexpr int IQ = CI / 4;         // input channels per lane (4 or 2)
    constexpr int NP = IQ / 2;         // packed pairs (2 or 1)
    const int gtid   = blockIdx.x * blockDim.x + threadIdx.x;
    const int wid    = gtid >> 6;
    const int nwaves = (gridDim.x * blockDim.x) >> 6;
    const int lane   = gtid & 63;
    const int eg     = lane >> 4;      // i-quarter 0..3
    const int o      = lane & 15;      // out channel

    // ---- hoisted per-lane constants (node-loop invariant) ----
    v2f W0[NP], W1[NP], W2[NP], Bv[NP], Rv[NP];
#pragma unroll
    for (int u = 0; u < NP; ++u) {
        float4 wa = wt_l[(eg * IQ + 2 * u) * 16 + o];
        float4 wb = wt_l[(eg * IQ + 2 * u + 1) * 16 + o];
        W0[u] = (v2f){wa.x, wb.x};
        W1[u] = (v2f){wa.y, wb.y};
        W2[u] = (v2f){wa.z, wb.z};
        Bv[u] = (v2f){wa.w, wb.w};
        Rv[u] = (v2f){root[(eg * IQ + 2 * u) * 16 + o],
                      root[(eg * IQ + 2 * u + 1) * 16 + o]};
    }
    const float bo = bias[o];
    const v2f zero = 0.f;

    for (int t = wid; t < N; t += nwaves) {
        const int deg = cnt[t];
        const int dl  = min(deg, DMAX);
        const float4* __restrict__ row = pdata + (size_t)t * DMAX;

        float4 pdA = row[0], pdB = row[1];   // preload pair 0 (garbage-safe)
        v2f vacc = 0.f;
        for (int p = 0; p < dl; p += 2) {
            const bool okB = (p + 1) < dl;
            const int sA = __float_as_int(pdA.w);
            const int sB = okB ? __float_as_int(pdB.w) : sA;
            v2f xA[NP], xB[NP];
            load_x<IQ>(h_in, sA, eg, xA);
            load_x<IQ>(h_in, sB, eg, xB);
            const int pn = min(p + 2, DMAX - 2);     // rotate: prefetch next pair
            float4 pdA2 = row[pn], pdB2 = row[pn + 1];
            v2f ax = pdA.x, ay = pdA.y, az = pdA.z;
            v2f bx = pdB.x, by = pdB.y, bz = pdB.z;
            v2f eA = 0.f, eB = 0.f;
#pragma unroll
            for (int u = 0; u < NP; ++u) {
                v2f wA = __builtin_elementwise_fma(az, W2[u],
                         __builtin_elementwise_fma(ay, W1[u],
                         __builtin_elementwise_fma(ax, W0[u], Bv[u])));
                wA = __builtin_elementwise_max(wA, zero);
                eA = __builtin_elementwise_fma(xA[u], wA, eA);
                v2f wB = __builtin_elementwise_fma(bz, W2[u],
                         __builtin_elementwise_fma(by, W1[u],
                         __builtin_elementwise_fma(bx, W0[u], Bv[u])));
                wB = __builtin_elementwise_max(wB, zero);
                eB = __builtin_elementwise_fma(xB[u], wB, eB);
            }
            vacc += eA + (okB ? eB : zero);
            pdA = pdA2; pdB = pdB2;
        }
        float acc = vacc.x + vacc.y;

        // root partial for this lane's i-quarter
        v2f xT[NP];
        load_x<IQ>(h_in, t, eg, xT);
        v2f rpv = 0.f;
#pragma unroll
        for (int u = 0; u < NP; ++u)
            rpv = __builtin_elementwise_fma(xT[u], Rv[u], rpv);
        float rp = rpv.x + rpv.y;

        // mean is linear: sum (acc/deg + rp) over the 4 i-quarter groups
        float contrib = fmaf(acc, 1.0f / fmaxf((float)deg, 1.0f), rp);
        contrib += __shfl_xor(contrib, 16);
        contrib += __shfl_xor(contrib, 32);

        if (eg == 0) h_out[t * 16 + o] = fmaxf(contrib + bo, 0.f);
    }
}

// ---------------------------------------------------------------------------
// Output gather: out = [h[idx] (M*16) | pos[idx] (M*3) | batch[idx] (M)]
// ---------------------------------------------------------------------------
__global__ __launch_bounds__(256) void gather_kernel(
    const float* __restrict__ h,
    const float* __restrict__ pos,
    const int*   __restrict__ batch,
    const int*   __restrict__ idx,
    float*       __restrict__ out,
    int M)
{
    int j = blockIdx.x * blockDim.x + threadIdx.x;
    if (j >= M) return;
    int n = idx[j];
    float4*       o4 = (float4*)out + (size_t)j * 4;
    const float4* h4 = (const float4*)(h + (size_t)n * 16);
    o4[0] = h4[0]; o4[1] = h4[1]; o4[2] = h4[2]; o4[3] = h4[3];
    float* po = out + (size_t)M * 16 + (size_t)j * 3;
    po[0] = pos[n * 3 + 0];
    po[1] = pos[n * 3 + 1];
    po[2] = pos[n * 3 + 2];
    ((int*)out)[(size_t)M * 19 + j] = batch[n];
}

extern "C" void kernel_launch(void* const* d_in, const int* in_sizes, int n_in,
                              void* d_out, int out_size, void* d_ws, size_t ws_size,
                              hipStream_t stream) {
    const float* x      = (const float*)d_in[0];
    const float* pos    = (const float*)d_in[1];
    const float* lin_w0 = (const float*)d_in[2];
    const float* lin_b0 = (const float*)d_in[3];
    const float* gamma0 = (const float*)d_in[4];
    const float* beta0  = (const float*)d_in[5];
    const float* root0  = (const float*)d_in[6];
    const float* bias0  = (const float*)d_in[7];
    const float* lin_w1 = (const float*)d_in[8];
    const float* lin_b1 = (const float*)d_in[9];
    const float* gamma1 = (const float*)d_in[10];
    const float* beta1  = (const float*)d_in[11];
    const float* root1  = (const float*)d_in[12];
    const float* bias1  = (const float*)d_in[13];
    const float* lin_w2 = (const float*)d_in[14];
    const float* lin_b2 = (const float*)d_in[15];
    const float* gamma2 = (const float*)d_in[16];
    const float* beta2  = (const float*)d_in[17];
    const float* root2  = (const float*)d_in[18];
    const float* bias2  = (const float*)d_in[19];
    const int*   batch  = (const int*)d_in[20];
    const int*   idx    = (const int*)d_in[21];
    const int*   ei     = (const int*)d_in[22];
    float*       out    = (float*)d_out;

    // workspace layout (all 16B aligned)
    float4* pdata = (float4*)d_ws;                                // N*DMAX float4 (51.2 MB)
    float*  hA    = (float*)(pdata + (size_t)N_NODES * DMAX);     // N*16 floats
    float*  hB    = hA + (size_t)N_NODES * 16;                    // N*16 floats
    int*    cnt   = (int*)(hB + (size_t)N_NODES * 16);            // N ints
    float4* wtab  = (float4*)(cnt + N_NODES);                     // 3*256 float4 (12 KB)

    hipMemsetAsync(cnt, 0, N_NODES * sizeof(int), stream);
    prep_kernel<<<(N_EDGES + 511) / 512, 256, 0, stream>>>(
        ei, pos, cnt, pdata,
        lin_w0, lin_b0, gamma0, beta0,
        lin_w1, lin_b1, gamma1, beta1,
        lin_w2, lin_b2, gamma2, beta2, wtab, N_EDGES);

    const int NB = 2048;   // 8192 persistent waves = 8 waves/SIMD exactly

    node_wave_kernel<8><<<NB, 256, 0, stream>>>(pdata, cnt, x,
        wtab, root0, bias0, hA, N_NODES);
    node_wave_kernel<16><<<NB, 256, 0, stream>>>(pdata, cnt, hA,
        wtab + 256, root1, bias1, hB, N_NODES);
    node_wave_kernel<16><<<NB, 256, 0, stream>>>(pdata, cnt, hB,
        wtab + 512, root2, bias2, hA, N_NODES);

    gather_kernel<<<(M_IDX + 255) / 256, 256, 0, stream>>>(hA, pos, batch, idx, out, M_IDX);
}